// Round 3
// baseline (163.792 us; speedup 1.0000x reference)
//
#include <hip/hip_runtime.h>

// out[i] = x[i] * scale. Memory-bound streaming scale:
//  - 16B/lane coalesced access via native clang vector type
//  - grid-stride loop, grid capped at 2048 blocks (256 CU * 8 blocks/CU)
//  - non-temporal load/store: data is touched exactly once, skip cache fill
typedef float f32x4 __attribute__((ext_vector_type(4)));

__global__ void __launch_bounds__(256) scale_f32x4_gs_kernel(
    const f32x4* __restrict__ x4, f32x4* __restrict__ o4, int n4, float scale) {
    const int stride = gridDim.x * blockDim.x;
    for (int i = blockIdx.x * blockDim.x + threadIdx.x; i < n4; i += stride) {
        f32x4 v = __builtin_nontemporal_load(&x4[i]);
        v *= scale;
        __builtin_nontemporal_store(v, &o4[i]);
    }
}

__global__ void scale_f32_tail_kernel(
    const float* __restrict__ x, float* __restrict__ o, int start, int n, float scale) {
    int i = start + blockIdx.x * blockDim.x + threadIdx.x;
    if (i < n) {
        o[i] = x[i] * scale;
    }
}

extern "C" void kernel_launch(void* const* d_in, const int* in_sizes, int n_in,
                              void* d_out, int out_size, void* d_ws, size_t ws_size,
                              hipStream_t stream) {
    const float* x = (const float*)d_in[0];
    float* out = (float*)d_out;
    const int n = in_sizes[0];

    // Reference: x / (H*W + 1e-9), H=W=224. Reciprocal computed in double,
    // rounded once to f32 (error ~1e-11 in output units, threshold 2.2e-6).
    const double denom = 224.0 * 224.0 + 1e-9;
    const float scale = (float)(1.0 / denom);

    const int n4 = n / 4;
    if (n4 > 0) {
        const int block = 256;
        int grid = (n4 + block - 1) / block;
        const int max_grid = 2048;  // 256 CUs x 8 blocks/CU
        if (grid > max_grid) grid = max_grid;
        scale_f32x4_gs_kernel<<<grid, block, 0, stream>>>(
            (const f32x4*)x, (f32x4*)out, n4, scale);
    }
    const int tail_start = n4 * 4;
    const int tail = n - tail_start;
    if (tail > 0) {
        scale_f32_tail_kernel<<<1, 64, 0, stream>>>(x, out, tail_start, n, scale);
    }
}

// Round 4
// 147.287 us; speedup vs baseline: 1.1121x; 1.1121x over previous
//
#include <hip/hip_runtime.h>

// out[i] = x[i] * scale. Memory-bound streaming scale.
//  - 16B/lane coalesced access, 4 float4 per thread (block-strided) so each
//    wave has 4 independent loads in flight before any store
//  - one-shot grid (no grid-stride loop): 25088 workgroups for this shape
typedef float f32x4 __attribute__((ext_vector_type(4)));

__global__ void __launch_bounds__(256) scale_f32x4_u4_kernel(
    const f32x4* __restrict__ x4, f32x4* __restrict__ o4, int n4, float scale) {
    const int i0 = blockIdx.x * (256 * 4) + threadIdx.x;
    if (i0 + 3 * 256 < n4) {
        // fast path: 4 independent coalesced loads, then 4 stores
        f32x4 a = x4[i0];
        f32x4 b = x4[i0 + 256];
        f32x4 c = x4[i0 + 512];
        f32x4 d = x4[i0 + 768];
        o4[i0]       = a * scale;
        o4[i0 + 256] = b * scale;
        o4[i0 + 512] = c * scale;
        o4[i0 + 768] = d * scale;
    } else {
        #pragma unroll
        for (int k = 0; k < 4; ++k) {
            const int i = i0 + k * 256;
            if (i < n4) o4[i] = x4[i] * scale;
        }
    }
}

__global__ void scale_f32_tail_kernel(
    const float* __restrict__ x, float* __restrict__ o, int start, int n, float scale) {
    int i = start + blockIdx.x * blockDim.x + threadIdx.x;
    if (i < n) {
        o[i] = x[i] * scale;
    }
}

extern "C" void kernel_launch(void* const* d_in, const int* in_sizes, int n_in,
                              void* d_out, int out_size, void* d_ws, size_t ws_size,
                              hipStream_t stream) {
    const float* x = (const float*)d_in[0];
    float* out = (float*)d_out;
    const int n = in_sizes[0];

    // Reference: x / (H*W + 1e-9), H=W=224. Reciprocal computed in double,
    // rounded once to f32 (error ~1e-11 in output units, threshold 2.2e-6).
    const double denom = 224.0 * 224.0 + 1e-9;
    const float scale = (float)(1.0 / denom);

    const int n4 = n / 4;
    if (n4 > 0) {
        const int block = 256;
        const int per_block = block * 4;  // 4 float4 per thread
        const int grid = (n4 + per_block - 1) / per_block;
        scale_f32x4_u4_kernel<<<grid, block, 0, stream>>>(
            (const f32x4*)x, (f32x4*)out, n4, scale);
    }
    const int tail_start = n4 * 4;
    const int tail = n - tail_start;
    if (tail > 0) {
        scale_f32_tail_kernel<<<1, 64, 0, stream>>>(x, out, tail_start, n, scale);
    }
}

// Round 5
// 140.588 us; speedup vs baseline: 1.1650x; 1.0476x over previous
//
#include <hip/hip_runtime.h>

// out[i] = x[i] * scale, vectorized float4. One element-quad per thread,
// one-shot grid. Empirically fastest variant on MI355X for this pure
// streaming op (139.6 us = 5.89 TB/s = 93.5% of measured 6.29 TB/s copy
// ceiling). Tried and rejected:
//  - grid-stride loop @2048 blocks + nontemporal: 163.8 us (-17%)
//  - 4 float4/thread block-strided ILP: 147.3 us (-5.5%)
// Wave churn (100k workgroups) beats per-thread ILP for pure streams here.
__global__ void __launch_bounds__(256) scale_f32x4_kernel(
    const float4* __restrict__ x4, float4* __restrict__ o4, int n4, float scale) {
    int i = blockIdx.x * blockDim.x + threadIdx.x;
    if (i < n4) {
        float4 v = x4[i];
        v.x *= scale;
        v.y *= scale;
        v.z *= scale;
        v.w *= scale;
        o4[i] = v;
    }
}

__global__ void scale_f32_tail_kernel(
    const float* __restrict__ x, float* __restrict__ o, int start, int n, float scale) {
    int i = start + blockIdx.x * blockDim.x + threadIdx.x;
    if (i < n) {
        o[i] = x[i] * scale;
    }
}

extern "C" void kernel_launch(void* const* d_in, const int* in_sizes, int n_in,
                              void* d_out, int out_size, void* d_ws, size_t ws_size,
                              hipStream_t stream) {
    const float* x = (const float*)d_in[0];
    float* out = (float*)d_out;
    const int n = in_sizes[0];

    // Reference: x / (H*W + 1e-9), H=W=224. Reciprocal computed in double,
    // rounded once to f32 (error ~1e-11 in output units, threshold 2.2e-6).
    const double denom = 224.0 * 224.0 + 1e-9;
    const float scale = (float)(1.0 / denom);

    const int n4 = n / 4;
    if (n4 > 0) {
        const int block = 256;
        const int grid = (n4 + block - 1) / block;
        scale_f32x4_kernel<<<grid, block, 0, stream>>>(
            (const float4*)x, (float4*)out, n4, scale);
    }
    const int tail_start = n4 * 4;
    const int tail = n - tail_start;
    if (tail > 0) {
        scale_f32_tail_kernel<<<1, 64, 0, stream>>>(x, out, tail_start, n, scale);
    }
}